// Round 1
// baseline (339.108 us; speedup 1.0000x reference)
//
#include <hip/hip_runtime.h>
#include <stdint.h>

// MHA forward, B=8 T=1024 C=1024 H=16 D=64.
// Pipeline: cast fp32->bf16 -> QKV GEMM (bf16 MFMA, m97-style global_load_lds)
//        -> flash attention (online softmax, MFMA QK^T and PV)
//        -> proj GEMM with fused bias (fp32 out).

#define Bn 8
#define Tn 1024
#define Cn 1024
#define Hn 16
#define Dn 64
#define Mn (Bn * Tn)      // 8192
#define NQKV (3 * Cn)     // 3072

typedef unsigned short u16;
typedef float f32x4 __attribute__((ext_vector_type(4)));
typedef __bf16 bf16x8 __attribute__((ext_vector_type(8)));
typedef unsigned short ushx8 __attribute__((ext_vector_type(8)));
typedef unsigned short ushx4 __attribute__((ext_vector_type(4)));

__device__ __forceinline__ u16 f2bf(float f) {
  unsigned int u = __float_as_uint(f);
  u += 0x7fffu + ((u >> 16) & 1u);   // RTN-even
  return (u16)(u >> 16);
}

__device__ __forceinline__ f32x4 mfma_bf16(ushx8 a, ushx8 b, f32x4 c) {
  return __builtin_amdgcn_mfma_f32_16x16x32_bf16(
      __builtin_bit_cast(bf16x8, a), __builtin_bit_cast(bf16x8, b), c, 0, 0, 0);
}

// async global->LDS, 16B per lane; LDS dest = wave-uniform base + lane*16 (m104)
__device__ __forceinline__ void async16(const u16* g, u16* l) {
  __builtin_amdgcn_global_load_lds(
      (__attribute__((address_space(1))) void*)(void*)g,
      (__attribute__((address_space(3))) void*)l, 16, 0, 0);
}

// ---------------- cast fp32 -> bf16 ----------------
__global__ void cast_kernel(const float* __restrict__ in, u16* __restrict__ out, int n4) {
  int i = blockIdx.x * blockDim.x + threadIdx.x;
  if (i < n4) {
    float4 v = ((const float4*)in)[i];
    ushx4 o = { f2bf(v.x), f2bf(v.y), f2bf(v.z), f2bf(v.w) };
    ((ushx4*)out)[i] = o;
  }
}

// ---------------- GEMM: C[m,n] = sum_k A[m,k]*Bw[n,k] (+bias) ----------------
// 128x128 tile, 4 waves -> 64x64 each, BK=32, mfma 16x16x32 bf16.
template <int WRITE_BF16>
__global__ __launch_bounds__(256, 2) void gemm_bt(
    const u16* __restrict__ A, const u16* __restrict__ Bw,
    void* __restrict__ Cout, const float* __restrict__ bias, int N, int K) {
  __shared__ alignas(16) u16 As[128 * 32];
  __shared__ alignas(16) u16 Bs[128 * 32];

  const int tid = threadIdx.x;
  const int lane = tid & 63;
  const int wv = tid >> 6;
  const int quad = lane >> 4;
  const int l16 = lane & 15;
  const int m0 = blockIdx.x * 128;
  const int n0 = blockIdx.y * 128;
  const int wm = (wv >> 1) * 64;
  const int wn = (wv & 1) * 64;

  f32x4 acc[4][4];
#pragma unroll
  for (int i = 0; i < 4; ++i)
#pragma unroll
    for (int j = 0; j < 4; ++j) acc[i][j] = (f32x4){0.f, 0.f, 0.f, 0.f};

  // staging geometry: chunk idx = call*256 + tid; row = idx>>2, cc = idx&3.
  // Global k-chunk is XOR-swizzled by row bits 1:2 to break LDS bank aliasing
  // on the fragment reads (LDS slot order is fixed by global_load_lds).
  const int r0 = tid >> 2;
  const int cc0 = tid & 3;
  const int gkc0 = cc0 ^ ((r0 >> 1) & 3);
  const int r1 = r0 + 64;
  const int gkc1 = cc0 ^ ((r1 >> 1) & 3);
  const u16* gA0 = A + (size_t)(m0 + r0) * K + gkc0 * 8;
  const u16* gA1 = A + (size_t)(m0 + r1) * K + gkc1 * 8;
  const u16* gB0 = Bw + (size_t)(n0 + r0) * K + gkc0 * 8;
  const u16* gB1 = Bw + (size_t)(n0 + r1) * K + gkc1 * 8;
  u16* lA0 = As + tid * 8;
  u16* lA1 = As + (256 + tid) * 8;
  u16* lB0 = Bs + tid * 8;
  u16* lB1 = Bs + (256 + tid) * 8;

  // fragment read pointers (row bits 1:2 == l16 bits 1:2, so swizzle term is mi-invariant)
  const u16* pa[4];
  const u16* pb[4];
#pragma unroll
  for (int mi = 0; mi < 4; ++mi) {
    int ra = wm + mi * 16 + l16;
    pa[mi] = As + ra * 32 + (quad ^ ((ra >> 1) & 3)) * 8;
    int rb = wn + mi * 16 + l16;
    pb[mi] = Bs + rb * 32 + (quad ^ ((rb >> 1) & 3)) * 8;
  }

  for (int k0 = 0; k0 < K; k0 += 32) {
    async16(gA0 + k0, lA0);
    async16(gA1 + k0, lA1);
    async16(gB0 + k0, lB0);
    async16(gB1 + k0, lB1);
    __syncthreads();
    ushx8 af[4], bf[4];
#pragma unroll
    for (int i = 0; i < 4; ++i) {
      af[i] = *(const ushx8*)pa[i];
      bf[i] = *(const ushx8*)pb[i];
    }
#pragma unroll
    for (int mi = 0; mi < 4; ++mi)
#pragma unroll
      for (int ni = 0; ni < 4; ++ni)
        acc[mi][ni] = mfma_bf16(af[mi], bf[ni], acc[mi][ni]);
    __syncthreads();
  }

  // epilogue: C/D layout row = quad*4+i, col = l16 (m89-verified)
#pragma unroll
  for (int mi = 0; mi < 4; ++mi) {
#pragma unroll
    for (int ni = 0; ni < 4; ++ni) {
      int col = n0 + wn + ni * 16 + l16;
      float bv = 0.f;
      if constexpr (!WRITE_BF16) bv = bias[col];
#pragma unroll
      for (int i = 0; i < 4; ++i) {
        int row = m0 + wm + mi * 16 + quad * 4 + i;
        float v = acc[mi][ni][i] + bv;
        if constexpr (WRITE_BF16)
          ((u16*)Cout)[(size_t)row * N + col] = f2bf(v);
        else
          ((float*)Cout)[(size_t)row * N + col] = v;
      }
    }
  }
}

// ---------------- flash attention ----------------
// block = 256 threads (4 waves), one 64-row q-tile of one (b,h).
// wave wv owns q rows [wv*16, wv*16+16). K/V tiles of 64 rows, causal.
__global__ __launch_bounds__(256, 2) void attn_kernel(
    const u16* __restrict__ qkv, u16* __restrict__ out) {
  const int qt = blockIdx.x, h = blockIdx.y, b = blockIdx.z;
  const int q0 = qt * 64;
  const int tid = threadIdx.x;
  const int lane = tid & 63;
  const int wv = tid >> 6;
  const int quad = lane >> 4;
  const int l16 = lane & 15;

  // +8 pad: row stride 144B = 9*16B -> 16B aligned, 2-way banks only (free, m136)
  __shared__ alignas(16) u16 Ks[64][72];
  __shared__ alignas(16) u16 Vt[64][72];   // Vt[dd][kv]
  __shared__ alignas(16) u16 Ps[4][16][72];

  const size_t rowbase = (size_t)b * Tn * NQKV;
  const u16* qb = qkv + rowbase + h * Dn;
  const u16* kb = qkv + rowbase + Cn + h * Dn;
  const u16* vb = qkv + rowbase + 2 * Cn + h * Dn;

  // Q fragments in registers (A-operand: m = l16, k = quad*8+j)
  ushx8 qf[2];
  {
    const u16* qp = qb + (size_t)(q0 + wv * 16 + l16) * NQKV + quad * 8;
    qf[0] = *(const ushx8*)qp;
    qf[1] = *(const ushx8*)(qp + 32);
  }

  f32x4 o[4];
#pragma unroll
  for (int nt = 0; nt < 4; ++nt) o[nt] = (f32x4){0.f, 0.f, 0.f, 0.f};
  float mrow[4], lrow[4];
#pragma unroll
  for (int i = 0; i < 4; ++i) { mrow[i] = -__builtin_inff(); lrow[i] = 0.f; }

  const int srow = tid >> 3;  // 0..31
  const int scc = tid & 7;

  for (int kv0 = 0; kv0 <= q0; kv0 += 64) {
    // stage K (row-major) and V (transposed) into LDS
#pragma unroll
    for (int cg = 0; cg < 2; ++cg) {
      int row = cg * 32 + srow;
      const u16* kp = kb + (size_t)(kv0 + row) * NQKV + scc * 8;
      ushx8 kvv = *(const ushx8*)kp;
      *(ushx8*)&Ks[row][scc * 8] = kvv;
      const u16* vp = vb + (size_t)(kv0 + row) * NQKV + scc * 8;
      ushx8 vvv = *(const ushx8*)vp;
#pragma unroll
      for (int e = 0; e < 8; ++e) Vt[scc * 8 + e][row] = vvv[e];
    }
    __syncthreads();

    // S = Q K^T  (B-operand: n = l16 -> K row, k = dd contiguous)
    f32x4 s[4];
#pragma unroll
    for (int nt = 0; nt < 4; ++nt) s[nt] = (f32x4){0.f, 0.f, 0.f, 0.f};
#pragma unroll
    for (int nt = 0; nt < 4; ++nt) {
      ushx8 b0 = *(const ushx8*)&Ks[nt * 16 + l16][quad * 8];
      s[nt] = mfma_bf16(qf[0], b0, s[nt]);
      ushx8 b1 = *(const ushx8*)&Ks[nt * 16 + l16][32 + quad * 8];
      s[nt] = mfma_bf16(qf[1], b1, s[nt]);
    }

    const bool diag = (kv0 == q0);
    float alpha[4];
#pragma unroll
    for (int i = 0; i < 4; ++i) {
      const int qr = wv * 16 + quad * 4 + i;  // q row rel. tile
      float rmax = -__builtin_inff();
#pragma unroll
      for (int nt = 0; nt < 4; ++nt) {
        float v = s[nt][i] * 0.125f;  // 1/sqrt(64)
        if (diag && (nt * 16 + l16) > qr) v = -__builtin_inff();
        s[nt][i] = v;
        rmax = fmaxf(rmax, v);
      }
      rmax = fmaxf(rmax, __shfl_xor(rmax, 1));
      rmax = fmaxf(rmax, __shfl_xor(rmax, 2));
      rmax = fmaxf(rmax, __shfl_xor(rmax, 4));
      rmax = fmaxf(rmax, __shfl_xor(rmax, 8));
      float mnew = fmaxf(mrow[i], rmax);
      float al = __expf(mrow[i] - mnew);
      mrow[i] = mnew;
      float rsum = 0.f;
#pragma unroll
      for (int nt = 0; nt < 4; ++nt) {
        float p = __expf(s[nt][i] - mnew);
        s[nt][i] = p;
        rsum += p;
      }
      rsum += __shfl_xor(rsum, 1);
      rsum += __shfl_xor(rsum, 2);
      rsum += __shfl_xor(rsum, 4);
      rsum += __shfl_xor(rsum, 8);
      lrow[i] = lrow[i] * al + rsum;
      alpha[i] = al;
    }

    // P: C-layout -> LDS -> A-layout (m120 pattern)
#pragma unroll
    for (int i = 0; i < 4; ++i)
#pragma unroll
      for (int nt = 0; nt < 4; ++nt)
        Ps[wv][quad * 4 + i][nt * 16 + l16] = f2bf(s[nt][i]);

#pragma unroll
    for (int nt = 0; nt < 4; ++nt)
#pragma unroll
      for (int i = 0; i < 4; ++i) o[nt][i] *= alpha[i];

    __syncthreads();  // Ps visible; all waves done with Ks

    ushx8 pf0 = *(const ushx8*)&Ps[wv][l16][quad * 8];
    ushx8 pf1 = *(const ushx8*)&Ps[wv][l16][32 + quad * 8];
#pragma unroll
    for (int nt = 0; nt < 4; ++nt) {
      ushx8 v0 = *(const ushx8*)&Vt[nt * 16 + l16][quad * 8];
      o[nt] = mfma_bf16(pf0, v0, o[nt]);
      ushx8 v1 = *(const ushx8*)&Vt[nt * 16 + l16][32 + quad * 8];
      o[nt] = mfma_bf16(pf1, v1, o[nt]);
    }
    __syncthreads();  // done with Vt before next staging
  }

  // O/l, write y_attn as (B,T,C) bf16
#pragma unroll
  for (int i = 0; i < 4; ++i) {
    float inv = 1.f / lrow[i];
    int t = q0 + wv * 16 + quad * 4 + i;
    u16* op = out + ((size_t)(b * Tn + t)) * Cn + h * Dn + l16;
#pragma unroll
    for (int nt = 0; nt < 4; ++nt) op[nt * 16] = f2bf(o[nt][i] * inv);
  }
}

// ---------------- launch ----------------
extern "C" void kernel_launch(void* const* d_in, const int* in_sizes, int n_in,
                              void* d_out, int out_size, void* d_ws, size_t ws_size,
                              hipStream_t stream) {
  const float* x = (const float*)d_in[0];
  const float* w_qkv = (const float*)d_in[1];
  const float* w_proj = (const float*)d_in[2];
  const float* b_proj = (const float*)d_in[3];
  float* out = (float*)d_out;
  char* ws = (char*)d_ws;

  u16* xb     = (u16*)(ws);                 // 8192*1024 bf16 = 16 MB
  u16* wqkvb  = (u16*)(ws + 16777216);      // 3072*1024 bf16 =  6 MB
  u16* wprojb = (u16*)(ws + 23068672);      // 1024*1024 bf16 =  2 MB
  u16* qkvb   = (u16*)(ws + 25165824);      // 8192*3072 bf16 = 48 MB
  u16* yb     = (u16*)(ws + 75497472);      // 8192*1024 bf16 = 16 MB

  cast_kernel<<<8192, 256, 0, stream>>>(x, xb, 2097152);
  cast_kernel<<<3072, 256, 0, stream>>>(w_qkv, wqkvb, 786432);
  cast_kernel<<<1024, 256, 0, stream>>>(w_proj, wprojb, 262144);

  gemm_bt<1><<<dim3(Mn / 128, NQKV / 128), 256, 0, stream>>>(
      xb, wqkvb, (void*)qkvb, nullptr, NQKV, Cn);

  attn_kernel<<<dim3(Tn / 64, Hn, Bn), 256, 0, stream>>>(qkvb, yb);

  gemm_bt<0><<<dim3(Mn / 128, Cn / 128), 256, 0, stream>>>(
      yb, wprojb, (void*)out, b_proj, Cn, Cn);
}

// Round 2
// 335.867 us; speedup vs baseline: 1.0097x; 1.0097x over previous
//
#include <hip/hip_runtime.h>
#include <stdint.h>

// MHA forward, B=8 T=1024 C=1024 H=16 D=64.
// cast fp32->bf16 -> QKV GEMM (bf16 MFMA) -> V transpose -> flash attention
// (128-row q-tiles, async K/V staging, online softmax) -> proj GEMM (+bias).

#define Bn 8
#define Tn 1024
#define Cn 1024
#define Hn 16
#define Dn 64
#define Mn (Bn * Tn)      // 8192
#define NQKV (3 * Cn)     // 3072

typedef unsigned short u16;
typedef float f32x4 __attribute__((ext_vector_type(4)));
typedef __bf16 bf16x8 __attribute__((ext_vector_type(8)));
typedef unsigned short ushx8 __attribute__((ext_vector_type(8)));
typedef unsigned short ushx4 __attribute__((ext_vector_type(4)));

__device__ __forceinline__ u16 f2bf(float f) {
  unsigned int u = __float_as_uint(f);
  u += 0x7fffu + ((u >> 16) & 1u);   // RTN-even
  return (u16)(u >> 16);
}

__device__ __forceinline__ f32x4 mfma_bf16(ushx8 a, ushx8 b, f32x4 c) {
  return __builtin_amdgcn_mfma_f32_16x16x32_bf16(
      __builtin_bit_cast(bf16x8, a), __builtin_bit_cast(bf16x8, b), c, 0, 0, 0);
}

// async global->LDS, 16B per lane; LDS dest = wave-uniform base + lane*16 (m104)
__device__ __forceinline__ void async16(const u16* g, u16* l) {
  __builtin_amdgcn_global_load_lds(
      (__attribute__((address_space(1))) void*)(void*)g,
      (__attribute__((address_space(3))) void*)l, 16, 0, 0);
}

// ---------------- cast fp32 -> bf16 ----------------
__global__ void cast_kernel(const float* __restrict__ in, u16* __restrict__ out, int n4) {
  int i = blockIdx.x * blockDim.x + threadIdx.x;
  if (i < n4) {
    float4 v = ((const float4*)in)[i];
    ushx4 o = { f2bf(v.x), f2bf(v.y), f2bf(v.z), f2bf(v.w) };
    ((ushx4*)out)[i] = o;
  }
}

// ---------------- GEMM: C[m,n] = sum_k A[m,k]*Bw[n,k] (+bias) ----------------
// (unchanged from round 1 — passing, not the bottleneck this round)
template <int WRITE_BF16>
__global__ __launch_bounds__(256, 2) void gemm_bt(
    const u16* __restrict__ A, const u16* __restrict__ Bw,
    void* __restrict__ Cout, const float* __restrict__ bias, int N, int K) {
  __shared__ alignas(16) u16 As[128 * 32];
  __shared__ alignas(16) u16 Bs[128 * 32];

  const int tid = threadIdx.x;
  const int lane = tid & 63;
  const int wv = tid >> 6;
  const int quad = lane >> 4;
  const int l16 = lane & 15;
  const int m0 = blockIdx.x * 128;
  const int n0 = blockIdx.y * 128;
  const int wm = (wv >> 1) * 64;
  const int wn = (wv & 1) * 64;

  f32x4 acc[4][4];
#pragma unroll
  for (int i = 0; i < 4; ++i)
#pragma unroll
    for (int j = 0; j < 4; ++j) acc[i][j] = (f32x4){0.f, 0.f, 0.f, 0.f};

  const int r0 = tid >> 2;
  const int cc0 = tid & 3;
  const int gkc0 = cc0 ^ ((r0 >> 1) & 3);
  const int r1 = r0 + 64;
  const int gkc1 = cc0 ^ ((r1 >> 1) & 3);
  const u16* gA0 = A + (size_t)(m0 + r0) * K + gkc0 * 8;
  const u16* gA1 = A + (size_t)(m0 + r1) * K + gkc1 * 8;
  const u16* gB0 = Bw + (size_t)(n0 + r0) * K + gkc0 * 8;
  const u16* gB1 = Bw + (size_t)(n0 + r1) * K + gkc1 * 8;
  u16* lA0 = As + tid * 8;
  u16* lA1 = As + (256 + tid) * 8;
  u16* lB0 = Bs + tid * 8;
  u16* lB1 = Bs + (256 + tid) * 8;

  const u16* pa[4];
  const u16* pb[4];
#pragma unroll
  for (int mi = 0; mi < 4; ++mi) {
    int ra = wm + mi * 16 + l16;
    pa[mi] = As + ra * 32 + (quad ^ ((ra >> 1) & 3)) * 8;
    int rb = wn + mi * 16 + l16;
    pb[mi] = Bs + rb * 32 + (quad ^ ((rb >> 1) & 3)) * 8;
  }

  for (int k0 = 0; k0 < K; k0 += 32) {
    async16(gA0 + k0, lA0);
    async16(gA1 + k0, lA1);
    async16(gB0 + k0, lB0);
    async16(gB1 + k0, lB1);
    __syncthreads();
    ushx8 af[4], bf[4];
#pragma unroll
    for (int i = 0; i < 4; ++i) {
      af[i] = *(const ushx8*)pa[i];
      bf[i] = *(const ushx8*)pb[i];
    }
#pragma unroll
    for (int mi = 0; mi < 4; ++mi)
#pragma unroll
      for (int ni = 0; ni < 4; ++ni)
        acc[mi][ni] = mfma_bf16(af[mi], bf[ni], acc[mi][ni]);
    __syncthreads();
  }

#pragma unroll
  for (int mi = 0; mi < 4; ++mi) {
#pragma unroll
    for (int ni = 0; ni < 4; ++ni) {
      int col = n0 + wn + ni * 16 + l16;
      float bv = 0.f;
      if constexpr (!WRITE_BF16) bv = bias[col];
#pragma unroll
      for (int i = 0; i < 4; ++i) {
        int row = m0 + wm + mi * 16 + quad * 4 + i;
        float v = acc[mi][ni][i] + bv;
        if constexpr (WRITE_BF16)
          ((u16*)Cout)[(size_t)row * N + col] = f2bf(v);
        else
          ((float*)Cout)[(size_t)row * N + col] = v;
      }
    }
  }
}

// ---------------- V transpose: qkv V part -> vt[b][h][d][t] ----------------
// coalesced 128B reads (lane = d), 16B/lane stores (L2 write-combines within block)
__global__ __launch_bounds__(256) void transpose_v(
    const u16* __restrict__ qkv, u16* __restrict__ vt) {
  const int t0 = blockIdx.x * 64, h = blockIdx.y, b = blockIdx.z;
  const int lane = threadIdx.x & 63;
  const int wv = threadIdx.x >> 6;
  const u16* vb = qkv + (size_t)b * Tn * NQKV + 2 * Cn + h * Dn + lane;
  u16* ob = vt + ((size_t)(b * Hn + h) * Dn + lane) * Tn + t0;
#pragma unroll
  for (int tc = 0; tc < 2; ++tc) {
    const int t = (wv + tc * 4) * 8;
    ushx8 vals;
#pragma unroll
    for (int e = 0; e < 8; ++e) vals[e] = vb[(size_t)(t0 + t + e) * NQKV];
    *(ushx8*)(ob + t) = vals;
  }
}

// ---------------- flash attention v2 ----------------
// block = 256 threads (4 waves), 128 q rows per block; wave wv owns rows
// [wv*32, wv*32+32) (2 m-tiles). K and V^T staged via global_load_lds with
// XOR chunk swizzle; Ps roundtrip is wave-local (no barrier; DS in-order).
#define SLOG2E 0.18033688011112042f   // 0.125 * log2(e); softmax in log2 domain

__global__ __launch_bounds__(256, 3) void attn_kernel(
    const u16* __restrict__ qkv, const u16* __restrict__ vt,
    u16* __restrict__ out) {
  const int qt = blockIdx.x, h = blockIdx.y, b = blockIdx.z;
  const int q0 = qt * 128;
  const int tid = threadIdx.x;
  const int lane = tid & 63;
  const int wv = tid >> 6;
  const int quad = lane >> 4;
  const int l16 = lane & 15;

  __shared__ alignas(16) u16 Ks[64 * 64];     // [kv][d], XOR-swizzled chunks
  __shared__ alignas(16) u16 Vts[64 * 64];    // [d][kv], XOR-swizzled chunks
  __shared__ alignas(16) u16 Ps[4][32 * 72];  // per-wave P, stride 72 (16B-aligned)

  const u16* qb = qkv + (size_t)b * Tn * NQKV + h * Dn;
  const u16* kb = qkv + (size_t)b * Tn * NQKV + Cn + h * Dn;
  const u16* vtb = vt + (size_t)(b * Hn + h) * Dn * Tn;

  // Q fragments in registers (A-operand: m=l16, k=quad*8+j)
  ushx8 qf[2][2];
#pragma unroll
  for (int mi = 0; mi < 2; ++mi) {
    const u16* qp = qb + (size_t)(q0 + wv * 32 + mi * 16 + l16) * NQKV + quad * 8;
    qf[mi][0] = *(const ushx8*)qp;
    qf[mi][1] = *(const ushx8*)(qp + 32);
  }

  f32x4 o[2][4];
#pragma unroll
  for (int mi = 0; mi < 2; ++mi)
#pragma unroll
    for (int nt = 0; nt < 4; ++nt) o[mi][nt] = (f32x4){0.f, 0.f, 0.f, 0.f};
  float mrow[2][4], lrow[2][4];
#pragma unroll
  for (int mi = 0; mi < 2; ++mi)
#pragma unroll
    for (int i = 0; i < 4; ++i) { mrow[mi][i] = -__builtin_inff(); lrow[mi][i] = 0.f; }

  const int srow = tid >> 3;  // 0..31
  const int scc = tid & 7;
  u16* pswv = Ps[wv];

  const int kvmax = q0 + 64;
  for (int kv0 = 0; kv0 <= kvmax; kv0 += 64) {
    // stage K tile and V^T tile (each 64x64 bf16) via async DMA, swizzled slots
#pragma unroll
    for (int c = 0; c < 2; ++c) {
      const int row = c * 32 + srow;
      const int gc = scc ^ (row & 7);
      async16(kb + (size_t)(kv0 + row) * NQKV + gc * 8, Ks + (c * 256 + tid) * 8);
      async16(vtb + (size_t)row * Tn + kv0 + gc * 8, Vts + (c * 256 + tid) * 8);
    }
    __syncthreads();  // compiler drains vmcnt before s_barrier

    // S = Q K^T : B-operand from Ks row rb, chunk g at slot g^(rb&7)
    f32x4 s[2][4];
#pragma unroll
    for (int mi = 0; mi < 2; ++mi)
#pragma unroll
      for (int nt = 0; nt < 4; ++nt) s[mi][nt] = (f32x4){0.f, 0.f, 0.f, 0.f};
#pragma unroll
    for (int nt = 0; nt < 4; ++nt) {
      const int rb = nt * 16 + l16;
      ushx8 b0 = *(const ushx8*)(Ks + rb * 64 + (quad ^ (rb & 7)) * 8);
      ushx8 b1 = *(const ushx8*)(Ks + rb * 64 + ((quad + 4) ^ (rb & 7)) * 8);
#pragma unroll
      for (int mi = 0; mi < 2; ++mi) {
        s[mi][nt] = mfma_bf16(qf[mi][0], b0, s[mi][nt]);
        s[mi][nt] = mfma_bf16(qf[mi][1], b1, s[mi][nt]);
      }
    }

    // online softmax (log2 domain), causal mask only near the diagonal
#pragma unroll
    for (int mi = 0; mi < 2; ++mi) {
      const bool dz = (kv0 + 64 > q0 + wv * 32 + mi * 16);
#pragma unroll
      for (int i = 0; i < 4; ++i) {
        const int qr = q0 + wv * 32 + mi * 16 + quad * 4 + i;
        float rmax = -__builtin_inff();
#pragma unroll
        for (int nt = 0; nt < 4; ++nt) {
          float v = s[mi][nt][i] * SLOG2E;
          if (dz && (kv0 + nt * 16 + l16) > qr) v = -__builtin_inff();
          s[mi][nt][i] = v;
          rmax = fmaxf(rmax, v);
        }
        rmax = fmaxf(rmax, __shfl_xor(rmax, 1));
        rmax = fmaxf(rmax, __shfl_xor(rmax, 2));
        rmax = fmaxf(rmax, __shfl_xor(rmax, 4));
        rmax = fmaxf(rmax, __shfl_xor(rmax, 8));
        const float mnew = fmaxf(mrow[mi][i], rmax);
        const float al = exp2f(mrow[mi][i] - mnew);
        mrow[mi][i] = mnew;
        float rsum = 0.f;
#pragma unroll
        for (int nt = 0; nt < 4; ++nt) {
          float p = exp2f(s[mi][nt][i] - mnew);
          s[mi][nt][i] = p;
          rsum += p;
        }
        rsum += __shfl_xor(rsum, 1);
        rsum += __shfl_xor(rsum, 2);
        rsum += __shfl_xor(rsum, 4);
        rsum += __shfl_xor(rsum, 8);
        lrow[mi][i] = lrow[mi][i] * al + rsum;
#pragma unroll
        for (int nt = 0; nt < 4; ++nt) o[mi][nt][i] *= al;
        // P: C-layout -> wave-local LDS (stride 72: 2-way write conflicts only)
#pragma unroll
        for (int nt = 0; nt < 4; ++nt)
          pswv[(mi * 16 + quad * 4 + i) * 72 + nt * 16 + l16] = f2bf(s[mi][nt][i]);
      }
    }

    // P A-fragments back from wave-local LDS (no barrier: DS in-order per wave)
    ushx8 pf[2][2];
#pragma unroll
    for (int mi = 0; mi < 2; ++mi) {
      const u16* pp = pswv + (mi * 16 + l16) * 72 + quad * 8;
      pf[mi][0] = *(const ushx8*)pp;
      pf[mi][1] = *(const ushx8*)(pp + 32);
    }

    // O += P V : B-operand from Vts row (d) rb, chunk g at slot g^(rb&7)
#pragma unroll
    for (int nt = 0; nt < 4; ++nt) {
      const int rb = nt * 16 + l16;
      ushx8 v0 = *(const ushx8*)(Vts + rb * 64 + (quad ^ (rb & 7)) * 8);
      ushx8 v1 = *(const ushx8*)(Vts + rb * 64 + ((quad + 4) ^ (rb & 7)) * 8);
#pragma unroll
      for (int mi = 0; mi < 2; ++mi) {
        o[mi][nt] = mfma_bf16(pf[mi][0], v0, o[mi][nt]);
        o[mi][nt] = mfma_bf16(pf[mi][1], v1, o[mi][nt]);
      }
    }
    __syncthreads();  // done with Ks/Vts before next tile's staging
  }

  // O/l, write y_attn as (B,T,C) bf16
#pragma unroll
  for (int mi = 0; mi < 2; ++mi) {
#pragma unroll
    for (int i = 0; i < 4; ++i) {
      const float inv = 1.f / lrow[mi][i];
      const int t = q0 + wv * 32 + mi * 16 + quad * 4 + i;
      u16* op = out + ((size_t)(b * Tn + t)) * Cn + h * Dn + l16;
#pragma unroll
      for (int nt = 0; nt < 4; ++nt) op[nt * 16] = f2bf(o[mi][nt][i] * inv);
    }
  }
}

// ---------------- launch ----------------
extern "C" void kernel_launch(void* const* d_in, const int* in_sizes, int n_in,
                              void* d_out, int out_size, void* d_ws, size_t ws_size,
                              hipStream_t stream) {
  const float* x = (const float*)d_in[0];
  const float* w_qkv = (const float*)d_in[1];
  const float* w_proj = (const float*)d_in[2];
  const float* b_proj = (const float*)d_in[3];
  float* out = (float*)d_out;
  char* ws = (char*)d_ws;

  u16* xb     = (u16*)(ws);                 // 8192*1024 bf16 = 16 MB (dead after QKV GEMM)
  u16* wqkvb  = (u16*)(ws + 16777216);      // 3072*1024 bf16 =  6 MB
  u16* wprojb = (u16*)(ws + 23068672);      // 1024*1024 bf16 =  2 MB
  u16* qkvb   = (u16*)(ws + 25165824);      // 8192*3072 bf16 = 48 MB
  u16* yb     = (u16*)(ws + 75497472);      // 8192*1024 bf16 = 16 MB
  u16* vtb    = (u16*)(ws);                 // 16 MB, reuses xb region (stream-ordered)

  cast_kernel<<<8192, 256, 0, stream>>>(x, xb, 2097152);
  cast_kernel<<<3072, 256, 0, stream>>>(w_qkv, wqkvb, 786432);
  cast_kernel<<<1024, 256, 0, stream>>>(w_proj, wprojb, 262144);

  gemm_bt<1><<<dim3(Mn / 128, NQKV / 128), 256, 0, stream>>>(
      xb, wqkvb, (void*)qkvb, nullptr, NQKV, Cn);

  transpose_v<<<dim3(Tn / 64, Hn, Bn), 256, 0, stream>>>(qkvb, vtb);

  attn_kernel<<<dim3(Tn / 128, Hn, Bn), 256, 0, stream>>>(qkvb, vtb, yb);

  gemm_bt<0><<<dim3(Mn / 128, Cn / 128), 256, 0, stream>>>(
      yb, wprojb, (void*)out, b_proj, Cn, Cn);
}

// Round 4
// 266.524 us; speedup vs baseline: 1.2723x; 1.2602x over previous
//
#include <hip/hip_runtime.h>
#include <stdint.h>

// MHA forward, B=8 T=1024 C=1024 H=16 D=64.
// cast fp32->bf16 -> QKV GEMM (bf16 MFMA) -> V transpose -> flash attention
// (balanced q-tile pairs, DPP softmax reductions, double-buffered DMA)
// -> proj GEMM (+bias).

#define Bn 8
#define Tn 1024
#define Cn 1024
#define Hn 16
#define Dn 64
#define Mn (Bn * Tn)      // 8192
#define NQKV (3 * Cn)     // 3072

typedef unsigned short u16;
typedef float f32x4 __attribute__((ext_vector_type(4)));
typedef __bf16 bf16x8 __attribute__((ext_vector_type(8)));
typedef unsigned short ushx8 __attribute__((ext_vector_type(8)));
typedef unsigned short ushx4 __attribute__((ext_vector_type(4)));

__device__ __forceinline__ u16 f2bf(float f) {
  unsigned int u = __float_as_uint(f);
  u += 0x7fffu + ((u >> 16) & 1u);   // RTN-even
  return (u16)(u >> 16);
}

__device__ __forceinline__ f32x4 mfma_bf16(ushx8 a, ushx8 b, f32x4 c) {
  return __builtin_amdgcn_mfma_f32_16x16x32_bf16(
      __builtin_bit_cast(bf16x8, a), __builtin_bit_cast(bf16x8, b), c, 0, 0, 0);
}

// async global->LDS, 16B per lane; LDS dest = wave-uniform base + lane*16 (m104)
__device__ __forceinline__ void async16(const u16* g, u16* l) {
  __builtin_amdgcn_global_load_lds(
      (__attribute__((address_space(1))) void*)(void*)g,
      (__attribute__((address_space(3))) void*)l, 16, 0, 0);
}

// ---- DPP 16-lane butterfly reductions (VALU-rate, no LDS pipe) ----
// CTRL must be an ICE: 0xB1=quad_perm(1,0,3,2)  0x4E=quad_perm(2,3,0,1)
//                      0x141=row_half_mirror    0x140=row_mirror
template <int CTRL>
__device__ __forceinline__ float dppmov(float v) {
  return __builtin_bit_cast(float, __builtin_amdgcn_update_dpp(
      0, __builtin_bit_cast(int, v), CTRL, 0xf, 0xf, true));
}
__device__ __forceinline__ float red16max(float v) {
  v = fmaxf(v, dppmov<0xB1>(v));
  v = fmaxf(v, dppmov<0x4E>(v));
  v = fmaxf(v, dppmov<0x141>(v));
  v = fmaxf(v, dppmov<0x140>(v));
  return v;
}
__device__ __forceinline__ float red16sum(float v) {
  v += dppmov<0xB1>(v);
  v += dppmov<0x4E>(v);
  v += dppmov<0x141>(v);
  v += dppmov<0x140>(v);
  return v;
}

// ---------------- cast fp32 -> bf16 ----------------
__global__ void cast_kernel(const float* __restrict__ in, u16* __restrict__ out, int n4) {
  int i = blockIdx.x * blockDim.x + threadIdx.x;
  if (i < n4) {
    float4 v = ((const float4*)in)[i];
    ushx4 o = { f2bf(v.x), f2bf(v.y), f2bf(v.z), f2bf(v.w) };
    ((ushx4*)out)[i] = o;
  }
}

// ---------------- GEMM: C[m,n] = sum_k A[m,k]*Bw[n,k] (+bias) ----------------
template <int WRITE_BF16>
__global__ __launch_bounds__(256, 2) void gemm_bt(
    const u16* __restrict__ A, const u16* __restrict__ Bw,
    void* __restrict__ Cout, const float* __restrict__ bias, int N, int K) {
  __shared__ alignas(16) u16 As[128 * 32];
  __shared__ alignas(16) u16 Bs[128 * 32];

  const int tid = threadIdx.x;
  const int lane = tid & 63;
  const int wv = tid >> 6;
  const int quad = lane >> 4;
  const int l16 = lane & 15;
  const int m0 = blockIdx.x * 128;
  const int n0 = blockIdx.y * 128;
  const int wm = (wv >> 1) * 64;
  const int wn = (wv & 1) * 64;

  f32x4 acc[4][4];
#pragma unroll
  for (int i = 0; i < 4; ++i)
#pragma unroll
    for (int j = 0; j < 4; ++j) acc[i][j] = (f32x4){0.f, 0.f, 0.f, 0.f};

  const int r0 = tid >> 2;
  const int cc0 = tid & 3;
  const int gkc0 = cc0 ^ ((r0 >> 1) & 3);
  const int r1 = r0 + 64;
  const int gkc1 = cc0 ^ ((r1 >> 1) & 3);
  const u16* gA0 = A + (size_t)(m0 + r0) * K + gkc0 * 8;
  const u16* gA1 = A + (size_t)(m0 + r1) * K + gkc1 * 8;
  const u16* gB0 = Bw + (size_t)(n0 + r0) * K + gkc0 * 8;
  const u16* gB1 = Bw + (size_t)(n0 + r1) * K + gkc1 * 8;
  u16* lA0 = As + tid * 8;
  u16* lA1 = As + (256 + tid) * 8;
  u16* lB0 = Bs + tid * 8;
  u16* lB1 = Bs + (256 + tid) * 8;

  const u16* pa[4];
  const u16* pb[4];
#pragma unroll
  for (int mi = 0; mi < 4; ++mi) {
    int ra = wm + mi * 16 + l16;
    pa[mi] = As + ra * 32 + (quad ^ ((ra >> 1) & 3)) * 8;
    int rb = wn + mi * 16 + l16;
    pb[mi] = Bs + rb * 32 + (quad ^ ((rb >> 1) & 3)) * 8;
  }

  for (int k0 = 0; k0 < K; k0 += 32) {
    async16(gA0 + k0, lA0);
    async16(gA1 + k0, lA1);
    async16(gB0 + k0, lB0);
    async16(gB1 + k0, lB1);
    __syncthreads();
    ushx8 af[4], bf[4];
#pragma unroll
    for (int i = 0; i < 4; ++i) {
      af[i] = *(const ushx8*)pa[i];
      bf[i] = *(const ushx8*)pb[i];
    }
#pragma unroll
    for (int mi = 0; mi < 4; ++mi)
#pragma unroll
      for (int ni = 0; ni < 4; ++ni)
        acc[mi][ni] = mfma_bf16(af[mi], bf[ni], acc[mi][ni]);
    __syncthreads();
  }

#pragma unroll
  for (int mi = 0; mi < 4; ++mi) {
#pragma unroll
    for (int ni = 0; ni < 4; ++ni) {
      int col = n0 + wn + ni * 16 + l16;
      float bv = 0.f;
      if constexpr (!WRITE_BF16) bv = bias[col];
#pragma unroll
      for (int i = 0; i < 4; ++i) {
        int row = m0 + wm + mi * 16 + quad * 4 + i;
        float v = acc[mi][ni][i] + bv;
        if constexpr (WRITE_BF16)
          ((u16*)Cout)[(size_t)row * N + col] = f2bf(v);
        else
          ((float*)Cout)[(size_t)row * N + col] = v;
      }
    }
  }
}

// ---------------- V transpose: qkv V part -> vt[b][h][d][t] ----------------
__global__ __launch_bounds__(256) void transpose_v(
    const u16* __restrict__ qkv, u16* __restrict__ vt) {
  const int t0 = blockIdx.x * 64, h = blockIdx.y, b = blockIdx.z;
  const int lane = threadIdx.x & 63;
  const int wv = threadIdx.x >> 6;
  const u16* vb = qkv + (size_t)b * Tn * NQKV + 2 * Cn + h * Dn + lane;
  u16* ob = vt + ((size_t)(b * Hn + h) * Dn + lane) * Tn + t0;
#pragma unroll
  for (int tc = 0; tc < 2; ++tc) {
    const int t = (wv + tc * 4) * 8;
    ushx8 vals;
#pragma unroll
    for (int e = 0; e < 8; ++e) vals[e] = vb[(size_t)(t0 + t + e) * NQKV];
    *(ushx8*)(ob + t) = vals;
  }
}

// ---------------- flash attention v3 ----------------
// 512 blocks (4,16,8); block j does q-tiles j and 7-j (18 kv-tiles total —
// perfectly balanced, exactly 2 blocks/CU). 4 waves, wave wv owns q rows
// [wv*32, wv*32+32) of the current 128-row tile. Double-buffered async K/V^T
// staging (1 barrier/tile); DPP softmax reductions; wave-local Ps roundtrip.
#define SLOG2E 0.18033688011112042f   // 0.125 * log2(e)

__global__ __launch_bounds__(256, 2) void attn_kernel(
    const u16* __restrict__ qkv, const u16* __restrict__ vt,
    u16* __restrict__ out) {
  const int j = blockIdx.x, h = blockIdx.y, b = blockIdx.z;
  const int tid = threadIdx.x;
  const int lane = tid & 63;
  const int wv = tid >> 6;
  const int quad = lane >> 4;
  const int l16 = lane & 15;

  __shared__ alignas(16) u16 Ks[2][64 * 64];   // [buf][kv][d] XOR-swizzled
  __shared__ alignas(16) u16 Vts[2][64 * 64];  // [buf][d][kv] XOR-swizzled
  __shared__ alignas(16) u16 Ps[4][32 * 72];   // per-wave P

  const u16* qb = qkv + (size_t)b * Tn * NQKV + h * Dn;
  const u16* kb = qkv + (size_t)b * Tn * NQKV + Cn + h * Dn;
  const u16* vtb = vt + (size_t)(b * Hn + h) * Dn * Tn;

  const int srow = tid >> 3;  // 0..31
  const int scc = tid & 7;
  u16* pswv = Ps[wv];

#pragma unroll 1
  for (int ph = 0; ph < 2; ++ph) {
    const int qt = ph ? (7 - j) : j;
    const int q0 = qt * 128;
    const int ntiles = 2 * qt + 2;

    // Q fragments (A-operand: m=l16, k=quad*8+jj)
    ushx8 qf[2][2];
#pragma unroll
    for (int mi = 0; mi < 2; ++mi) {
      const u16* qp = qb + (size_t)(q0 + wv * 32 + mi * 16 + l16) * NQKV + quad * 8;
      qf[mi][0] = *(const ushx8*)qp;
      qf[mi][1] = *(const ushx8*)(qp + 32);
    }

    f32x4 o[2][4];
#pragma unroll
    for (int mi = 0; mi < 2; ++mi)
#pragma unroll
      for (int nt = 0; nt < 4; ++nt) o[mi][nt] = (f32x4){0.f, 0.f, 0.f, 0.f};
    float mrow[2][4], lrow[2][4];
#pragma unroll
    for (int mi = 0; mi < 2; ++mi)
#pragma unroll
      for (int i = 0; i < 4; ++i) { mrow[mi][i] = -__builtin_inff(); lrow[mi][i] = 0.f; }

    __syncthreads();  // previous phase's compute done before overwriting buf0

    // prefetch tile 0 -> buf 0
#pragma unroll
    for (int c = 0; c < 2; ++c) {
      const int row = c * 32 + srow;
      const int gc = scc ^ (row & 7);
      async16(kb + (size_t)row * NQKV + gc * 8, Ks[0] + (c * 256 + tid) * 8);
      async16(vtb + (size_t)row * Tn + gc * 8, Vts[0] + (c * 256 + tid) * 8);
    }

#pragma unroll 1
    for (int t = 0; t < ntiles; ++t) {
      const int kv0 = t * 64;
      const int bi = t & 1;
      __syncthreads();  // drains DMA for buf[bi]; all waves done with buf[bi^1]

      // issue next tile's DMA into the other buffer (overlaps with compute)
      if (t + 1 < ntiles) {
        const int nkv0 = kv0 + 64;
        u16* kd = Ks[bi ^ 1];
        u16* vd = Vts[bi ^ 1];
#pragma unroll
        for (int c = 0; c < 2; ++c) {
          const int row = c * 32 + srow;
          const int gc = scc ^ (row & 7);
          async16(kb + (size_t)(nkv0 + row) * NQKV + gc * 8, kd + (c * 256 + tid) * 8);
          async16(vtb + (size_t)row * Tn + nkv0 + gc * 8, vd + (c * 256 + tid) * 8);
        }
      }

      // S = Q K^T
      const u16* ks = Ks[bi];
      const u16* vs = Vts[bi];
      f32x4 s[2][4];
#pragma unroll
      for (int mi = 0; mi < 2; ++mi)
#pragma unroll
        for (int nt = 0; nt < 4; ++nt) s[mi][nt] = (f32x4){0.f, 0.f, 0.f, 0.f};
#pragma unroll
      for (int nt = 0; nt < 4; ++nt) {
        const int rb = nt * 16 + l16;
        ushx8 b0 = *(const ushx8*)(ks + rb * 64 + (quad ^ (rb & 7)) * 8);
        ushx8 b1 = *(const ushx8*)(ks + rb * 64 + ((quad + 4) ^ (rb & 7)) * 8);
#pragma unroll
        for (int mi = 0; mi < 2; ++mi) {
          s[mi][nt] = mfma_bf16(qf[mi][0], b0, s[mi][nt]);
          s[mi][nt] = mfma_bf16(qf[mi][1], b1, s[mi][nt]);
        }
      }

      // online softmax, log2 domain; DPP reductions (no LDS-pipe shuffles)
#pragma unroll
      for (int mi = 0; mi < 2; ++mi) {
        const bool dz = (kv0 + 64 > q0 + wv * 32 + mi * 16);
#pragma unroll
        for (int i = 0; i < 4; ++i) {
          const int qr = q0 + wv * 32 + mi * 16 + quad * 4 + i;
          float vv[4];
          float rmax = -__builtin_inff();
#pragma unroll
          for (int nt = 0; nt < 4; ++nt) {
            float v = s[mi][nt][i] * SLOG2E;
            if (dz && (kv0 + nt * 16 + l16) > qr) v = -__builtin_inff();
            vv[nt] = v;
            rmax = fmaxf(rmax, v);
          }
          rmax = red16max(rmax);
          const float mnew = fmaxf(mrow[mi][i], rmax);
          const float al = exp2f(mrow[mi][i] - mnew);
          mrow[mi][i] = mnew;
          float rsum = 0.f;
#pragma unroll
          for (int nt = 0; nt < 4; ++nt) {
            float p = exp2f(vv[nt] - mnew);
            rsum += p;
            pswv[(mi * 16 + quad * 4 + i) * 72 + nt * 16 + l16] = f2bf(p);
          }
          rsum = red16sum(rsum);
          lrow[mi][i] = lrow[mi][i] * al + rsum;
#pragma unroll
          for (int nt = 0; nt < 4; ++nt) o[mi][nt][i] *= al;
        }
      }

      // P A-fragments from wave-local LDS (DS in-order per wave, no barrier)
      ushx8 pf[2][2];
#pragma unroll
      for (int mi = 0; mi < 2; ++mi) {
        const u16* pp = pswv + (mi * 16 + l16) * 72 + quad * 8;
        pf[mi][0] = *(const ushx8*)pp;
        pf[mi][1] = *(const ushx8*)(pp + 32);
      }

      // O += P V
#pragma unroll
      for (int nt = 0; nt < 4; ++nt) {
        const int rb = nt * 16 + l16;
        ushx8 v0 = *(const ushx8*)(vs + rb * 64 + (quad ^ (rb & 7)) * 8);
        ushx8 v1 = *(const ushx8*)(vs + rb * 64 + ((quad + 4) ^ (rb & 7)) * 8);
#pragma unroll
        for (int mi = 0; mi < 2; ++mi) {
          o[mi][nt] = mfma_bf16(pf[mi][0], v0, o[mi][nt]);
          o[mi][nt] = mfma_bf16(pf[mi][1], v1, o[mi][nt]);
        }
      }
    }

    // O/l, write y_attn as (B,T,C) bf16
#pragma unroll
    for (int mi = 0; mi < 2; ++mi) {
#pragma unroll
      for (int i = 0; i < 4; ++i) {
        const float inv = 1.f / lrow[mi][i];
        const int t = q0 + wv * 32 + mi * 16 + quad * 4 + i;
        u16* op = out + ((size_t)(b * Tn + t)) * Cn + h * Dn + l16;
#pragma unroll
        for (int nt = 0; nt < 4; ++nt) op[nt * 16] = f2bf(o[mi][nt][i] * inv);
      }
    }
  }
}

// ---------------- launch ----------------
extern "C" void kernel_launch(void* const* d_in, const int* in_sizes, int n_in,
                              void* d_out, int out_size, void* d_ws, size_t ws_size,
                              hipStream_t stream) {
  const float* x = (const float*)d_in[0];
  const float* w_qkv = (const float*)d_in[1];
  const float* w_proj = (const float*)d_in[2];
  const float* b_proj = (const float*)d_in[3];
  float* out = (float*)d_out;
  char* ws = (char*)d_ws;

  u16* xb     = (u16*)(ws);                 // 16 MB (dead after QKV GEMM)
  u16* wqkvb  = (u16*)(ws + 16777216);      //  6 MB
  u16* wprojb = (u16*)(ws + 23068672);      //  2 MB
  u16* qkvb   = (u16*)(ws + 25165824);      // 48 MB
  u16* yb     = (u16*)(ws + 75497472);      // 16 MB
  u16* vtb    = (u16*)(ws);                 // 16 MB, reuses xb (stream-ordered)

  cast_kernel<<<8192, 256, 0, stream>>>(x, xb, 2097152);
  cast_kernel<<<3072, 256, 0, stream>>>(w_qkv, wqkvb, 786432);
  cast_kernel<<<1024, 256, 0, stream>>>(w_proj, wprojb, 262144);

  gemm_bt<1><<<dim3(Mn / 128, NQKV / 128), 256, 0, stream>>>(
      xb, wqkvb, (void*)qkvb, nullptr, NQKV, Cn);

  transpose_v<<<dim3(Tn / 64, Hn, Bn), 256, 0, stream>>>(qkvb, vtb);

  attn_kernel<<<dim3(4, Hn, Bn), 256, 0, stream>>>(qkvb, vtb, yb);

  gemm_bt<0><<<dim3(Mn / 128, Cn / 128), 256, 0, stream>>>(
      yb, wprojb, (void*)out, b_proj, Cn, Cn);
}

// Round 5
// 252.888 us; speedup vs baseline: 1.3409x; 1.0539x over previous
//
#include <hip/hip_runtime.h>
#include <stdint.h>

// MHA forward, B=8 T=1024 C=1024 H=16 D=64.
// fused cast fp32->bf16 -> QKV GEMM (bf16 MFMA, Q pre-scaled by 0.125*log2e)
// -> V transpose -> flash attention (64-row q-tile pairs, 3 blocks/CU,
// raw v_exp_f32 softmax, double-buffered DMA) -> proj GEMM (+bias).

#define Bn 8
#define Tn 1024
#define Cn 1024
#define Hn 16
#define Dn 64
#define Mn (Bn * Tn)      // 8192
#define NQKV (3 * Cn)     // 3072

typedef unsigned short u16;
typedef float f32x4 __attribute__((ext_vector_type(4)));
typedef __bf16 bf16x8 __attribute__((ext_vector_type(8)));
typedef unsigned short ushx8 __attribute__((ext_vector_type(8)));
typedef unsigned short ushx4 __attribute__((ext_vector_type(4)));

__device__ __forceinline__ u16 f2bf(float f) {
  unsigned int u = __float_as_uint(f);
  u += 0x7fffu + ((u >> 16) & 1u);   // RTN-even
  return (u16)(u >> 16);
}
// round-nearest ties-away: 2 VALU ops; fine for P in [0,1]
__device__ __forceinline__ u16 f2bf_rna(float f) {
  return (u16)((__float_as_uint(f) + 0x8000u) >> 16);
}

__device__ __forceinline__ f32x4 mfma_bf16(ushx8 a, ushx8 b, f32x4 c) {
  return __builtin_amdgcn_mfma_f32_16x16x32_bf16(
      __builtin_bit_cast(bf16x8, a), __builtin_bit_cast(bf16x8, b), c, 0, 0, 0);
}

// async global->LDS, 16B per lane; LDS dest = wave-uniform base + lane*16 (m104)
__device__ __forceinline__ void async16(const u16* g, u16* l) {
  __builtin_amdgcn_global_load_lds(
      (__attribute__((address_space(1))) void*)(void*)g,
      (__attribute__((address_space(3))) void*)l, 16, 0, 0);
}

// ---- DPP 16-lane butterfly reductions (VALU-rate, no LDS pipe) ----
template <int CTRL>
__device__ __forceinline__ float dppmov(float v) {
  return __builtin_bit_cast(float, __builtin_amdgcn_update_dpp(
      0, __builtin_bit_cast(int, v), CTRL, 0xf, 0xf, true));
}
__device__ __forceinline__ float red16max(float v) {
  v = fmaxf(v, dppmov<0xB1>(v));
  v = fmaxf(v, dppmov<0x4E>(v));
  v = fmaxf(v, dppmov<0x141>(v));
  v = fmaxf(v, dppmov<0x140>(v));
  return v;
}
__device__ __forceinline__ float red16sum(float v) {
  v += dppmov<0xB1>(v);
  v += dppmov<0x4E>(v);
  v += dppmov<0x141>(v);
  v += dppmov<0x140>(v);
  return v;
}

// ---------------- fused cast fp32 -> bf16 (3 tensors, 1 launch) ----------------
__global__ void cast3_kernel(const float* __restrict__ a, u16* __restrict__ oa, int na4,
                             const float* __restrict__ b, u16* __restrict__ ob, int nb4,
                             const float* __restrict__ c, u16* __restrict__ oc, int nc4) {
  int i = blockIdx.x * blockDim.x + threadIdx.x;
  const float* in;
  u16* out;
  if (i < na4) { in = a; out = oa; }
  else if (i < na4 + nb4) { in = b; out = ob; i -= na4; }
  else if (i < na4 + nb4 + nc4) { in = c; out = oc; i -= na4 + nb4; }
  else return;
  float4 v = ((const float4*)in)[i];
  ushx4 o = { f2bf(v.x), f2bf(v.y), f2bf(v.z), f2bf(v.w) };
  ((ushx4*)out)[i] = o;
}

// ---------------- GEMM: C[m,n] = sum_k A[m,k]*Bw[n,k] (+bias) ----------------
// SCALE_Q: multiply cols [0,Cn) by 0.125*log2e (pre-scales Q for log2 softmax)
#define SLOG2E 0.18033688011112042f
template <int WRITE_BF16, int SCALE_Q>
__global__ __launch_bounds__(256, 3) void gemm_bt(
    const u16* __restrict__ A, const u16* __restrict__ Bw,
    void* __restrict__ Cout, const float* __restrict__ bias, int N, int K) {
  __shared__ alignas(16) u16 As[128 * 32];
  __shared__ alignas(16) u16 Bs[128 * 32];

  const int tid = threadIdx.x;
  const int lane = tid & 63;
  const int wv = tid >> 6;
  const int quad = lane >> 4;
  const int l16 = lane & 15;
  const int m0 = blockIdx.x * 128;
  const int n0 = blockIdx.y * 128;
  const int wm = (wv >> 1) * 64;
  const int wn = (wv & 1) * 64;

  f32x4 acc[4][4];
#pragma unroll
  for (int i = 0; i < 4; ++i)
#pragma unroll
    for (int j = 0; j < 4; ++j) acc[i][j] = (f32x4){0.f, 0.f, 0.f, 0.f};

  const int r0 = tid >> 2;
  const int cc0 = tid & 3;
  const int gkc0 = cc0 ^ ((r0 >> 1) & 3);
  const int r1 = r0 + 64;
  const int gkc1 = cc0 ^ ((r1 >> 1) & 3);
  const u16* gA0 = A + (size_t)(m0 + r0) * K + gkc0 * 8;
  const u16* gA1 = A + (size_t)(m0 + r1) * K + gkc1 * 8;
  const u16* gB0 = Bw + (size_t)(n0 + r0) * K + gkc0 * 8;
  const u16* gB1 = Bw + (size_t)(n0 + r1) * K + gkc1 * 8;
  u16* lA0 = As + tid * 8;
  u16* lA1 = As + (256 + tid) * 8;
  u16* lB0 = Bs + tid * 8;
  u16* lB1 = Bs + (256 + tid) * 8;

  const u16* pa[4];
  const u16* pb[4];
#pragma unroll
  for (int mi = 0; mi < 4; ++mi) {
    int ra = wm + mi * 16 + l16;
    pa[mi] = As + ra * 32 + (quad ^ ((ra >> 1) & 3)) * 8;
    int rb = wn + mi * 16 + l16;
    pb[mi] = Bs + rb * 32 + (quad ^ ((rb >> 1) & 3)) * 8;
  }

  for (int k0 = 0; k0 < K; k0 += 32) {
    async16(gA0 + k0, lA0);
    async16(gA1 + k0, lA1);
    async16(gB0 + k0, lB0);
    async16(gB1 + k0, lB1);
    __syncthreads();
    ushx8 af[4], bf[4];
#pragma unroll
    for (int i = 0; i < 4; ++i) {
      af[i] = *(const ushx8*)pa[i];
      bf[i] = *(const ushx8*)pb[i];
    }
#pragma unroll
    for (int mi = 0; mi < 4; ++mi)
#pragma unroll
      for (int ni = 0; ni < 4; ++ni)
        acc[mi][ni] = mfma_bf16(af[mi], bf[ni], acc[mi][ni]);
    __syncthreads();
  }

#pragma unroll
  for (int mi = 0; mi < 4; ++mi) {
#pragma unroll
    for (int ni = 0; ni < 4; ++ni) {
      int col = n0 + wn + ni * 16 + l16;
      float bv = 0.f;
      if constexpr (!WRITE_BF16) bv = bias[col];
      float sc = 1.f;
      if constexpr (SCALE_Q) sc = (col < Cn) ? SLOG2E : 1.f;
#pragma unroll
      for (int i = 0; i < 4; ++i) {
        int row = m0 + wm + mi * 16 + quad * 4 + i;
        float v = acc[mi][ni][i];
        if constexpr (SCALE_Q) v *= sc;
        v += bv;
        if constexpr (WRITE_BF16)
          ((u16*)Cout)[(size_t)row * N + col] = f2bf(v);
        else
          ((float*)Cout)[(size_t)row * N + col] = v;
      }
    }
  }
}

// ---------------- V transpose: qkv V part -> vt[b][h][d][t] ----------------
__global__ __launch_bounds__(256) void transpose_v(
    const u16* __restrict__ qkv, u16* __restrict__ vt) {
  const int t0 = blockIdx.x * 64, h = blockIdx.y, b = blockIdx.z;
  const int lane = threadIdx.x & 63;
  const int wv = threadIdx.x >> 6;
  const u16* vb = qkv + (size_t)b * Tn * NQKV + 2 * Cn + h * Dn + lane;
  u16* ob = vt + ((size_t)(b * Hn + h) * Dn + lane) * Tn + t0;
#pragma unroll
  for (int tc = 0; tc < 2; ++tc) {
    const int t = (wv + tc * 4) * 8;
    ushx8 vals;
#pragma unroll
    for (int e = 0; e < 8; ++e) vals[e] = vb[(size_t)(t0 + t + e) * NQKV];
    *(ushx8*)(ob + t) = vals;
  }
}

// ---------------- flash attention v4 ----------------
// 1024 blocks (8,16,8); block j does 64-row q-tiles j and 15-j (17 kv-tiles —
// perfectly balanced). LDS 41KB -> 3 blocks/CU. Wave wv owns q rows
// [wv*16, wv*16+16). Double-buffered async K/V^T staging; DPP reductions;
// raw v_exp_f32; Q pre-scaled in QKV GEMM (S already in log2 domain).
__global__ __launch_bounds__(256, 3) void attn_kernel(
    const u16* __restrict__ qkv, const u16* __restrict__ vt,
    u16* __restrict__ out) {
  const int j = blockIdx.x, h = blockIdx.y, b = blockIdx.z;
  const int tid = threadIdx.x;
  const int lane = tid & 63;
  const int wv = tid >> 6;
  const int quad = lane >> 4;
  const int l16 = lane & 15;

  __shared__ alignas(16) u16 Ks[2][64 * 64];   // [buf][kv][d] XOR-swizzled
  __shared__ alignas(16) u16 Vts[2][64 * 64];  // [buf][d][kv] XOR-swizzled
  __shared__ alignas(16) u16 Ps[4][16 * 72];   // per-wave P

  const u16* qb = qkv + (size_t)b * Tn * NQKV + h * Dn;
  const u16* kb = qkv + (size_t)b * Tn * NQKV + Cn + h * Dn;
  const u16* vtb = vt + (size_t)(b * Hn + h) * Dn * Tn;

  const int srow = tid >> 3;  // 0..31
  const int scc = tid & 7;
  u16* pswv = Ps[wv];

#pragma unroll 1
  for (int ph = 0; ph < 2; ++ph) {
    const int qt = ph ? (15 - j) : j;
    const int q0 = qt * 64;
    const int ntiles = qt + 1;

    // Q fragments (A-operand: m=l16, k=quad*8+jj); already scaled by SLOG2E
    ushx8 qf[2];
    {
      const u16* qp = qb + (size_t)(q0 + wv * 16 + l16) * NQKV + quad * 8;
      qf[0] = *(const ushx8*)qp;
      qf[1] = *(const ushx8*)(qp + 32);
    }

    f32x4 o[4];
#pragma unroll
    for (int nt = 0; nt < 4; ++nt) o[nt] = (f32x4){0.f, 0.f, 0.f, 0.f};
    float mrow[4], lrow[4];
#pragma unroll
    for (int i = 0; i < 4; ++i) { mrow[i] = -__builtin_inff(); lrow[i] = 0.f; }

    __syncthreads();  // previous phase's compute done before overwriting buf0

    // prefetch tile 0 -> buf 0
#pragma unroll
    for (int c = 0; c < 2; ++c) {
      const int row = c * 32 + srow;
      const int gc = scc ^ (row & 7);
      async16(kb + (size_t)row * NQKV + gc * 8, Ks[0] + (c * 256 + tid) * 8);
      async16(vtb + (size_t)row * Tn + gc * 8, Vts[0] + (c * 256 + tid) * 8);
    }

#pragma unroll 1
    for (int t = 0; t < ntiles; ++t) {
      const int kv0 = t * 64;
      const int bi = t & 1;
      __syncthreads();  // drains DMA for buf[bi]; all waves done with buf[bi^1]

      if (t + 1 < ntiles) {
        const int nkv0 = kv0 + 64;
        u16* kd = Ks[bi ^ 1];
        u16* vd = Vts[bi ^ 1];
#pragma unroll
        for (int c = 0; c < 2; ++c) {
          const int row = c * 32 + srow;
          const int gc = scc ^ (row & 7);
          async16(kb + (size_t)(nkv0 + row) * NQKV + gc * 8, kd + (c * 256 + tid) * 8);
          async16(vtb + (size_t)row * Tn + nkv0 + gc * 8, vd + (c * 256 + tid) * 8);
        }
      }

      // S = Q K^T (already log2-scaled via Q)
      const u16* ks = Ks[bi];
      const u16* vs = Vts[bi];
      f32x4 s[4];
#pragma unroll
      for (int nt = 0; nt < 4; ++nt) s[nt] = (f32x4){0.f, 0.f, 0.f, 0.f};
#pragma unroll
      for (int nt = 0; nt < 4; ++nt) {
        const int rb = nt * 16 + l16;
        ushx8 b0 = *(const ushx8*)(ks + rb * 64 + (quad ^ (rb & 7)) * 8);
        ushx8 b1 = *(const ushx8*)(ks + rb * 64 + ((quad + 4) ^ (rb & 7)) * 8);
        s[nt] = mfma_bf16(qf[0], b0, s[nt]);
        s[nt] = mfma_bf16(qf[1], b1, s[nt]);
      }

      // online softmax (log2 domain), DPP reductions, raw v_exp_f32
      const bool dz = (kv0 + 64 > q0 + wv * 16);
#pragma unroll
      for (int i = 0; i < 4; ++i) {
        const int qr = q0 + wv * 16 + quad * 4 + i;
        float vv[4];
        float rmax = -__builtin_inff();
#pragma unroll
        for (int nt = 0; nt < 4; ++nt) {
          float v = s[nt][i];
          if (dz && (kv0 + nt * 16 + l16) > qr) v = -__builtin_inff();
          vv[nt] = v;
          rmax = fmaxf(rmax, v);
        }
        rmax = red16max(rmax);
        const float mnew = fmaxf(mrow[i], rmax);
        const float al = __builtin_amdgcn_exp2f(mrow[i] - mnew);
        mrow[i] = mnew;
        float rsum = 0.f;
#pragma unroll
        for (int nt = 0; nt < 4; ++nt) {
          float p = __builtin_amdgcn_exp2f(vv[nt] - mnew);
          rsum += p;
          pswv[(quad * 4 + i) * 72 + nt * 16 + l16] = f2bf_rna(p);
        }
        rsum = red16sum(rsum);
        lrow[i] = lrow[i] * al + rsum;
#pragma unroll
        for (int nt = 0; nt < 4; ++nt) o[nt][i] *= al;
      }

      // P A-fragments from wave-local LDS (DS in-order per wave, no barrier)
      ushx8 pf0, pf1;
      {
        const u16* pp = pswv + l16 * 72 + quad * 8;
        pf0 = *(const ushx8*)pp;
        pf1 = *(const ushx8*)(pp + 32);
      }

      // O += P V
#pragma unroll
      for (int nt = 0; nt < 4; ++nt) {
        const int rb = nt * 16 + l16;
        ushx8 v0 = *(const ushx8*)(vs + rb * 64 + (quad ^ (rb & 7)) * 8);
        ushx8 v1 = *(const ushx8*)(vs + rb * 64 + ((quad + 4) ^ (rb & 7)) * 8);
        o[nt] = mfma_bf16(pf0, v0, o[nt]);
        o[nt] = mfma_bf16(pf1, v1, o[nt]);
      }
    }

    // O/l, write y_attn as (B,T,C) bf16
#pragma unroll
    for (int i = 0; i < 4; ++i) {
      const float inv = 1.f / lrow[i];
      const int t = q0 + wv * 16 + quad * 4 + i;
      u16* op = out + ((size_t)(b * Tn + t)) * Cn + h * Dn + l16;
#pragma unroll
      for (int nt = 0; nt < 4; ++nt) op[nt * 16] = f2bf(o[nt][i] * inv);
    }
  }
}

// ---------------- launch ----------------
extern "C" void kernel_launch(void* const* d_in, const int* in_sizes, int n_in,
                              void* d_out, int out_size, void* d_ws, size_t ws_size,
                              hipStream_t stream) {
  const float* x = (const float*)d_in[0];
  const float* w_qkv = (const float*)d_in[1];
  const float* w_proj = (const float*)d_in[2];
  const float* b_proj = (const float*)d_in[3];
  float* out = (float*)d_out;
  char* ws = (char*)d_ws;

  u16* xb     = (u16*)(ws);                 // 16 MB (dead after QKV GEMM)
  u16* wqkvb  = (u16*)(ws + 16777216);      //  6 MB
  u16* wprojb = (u16*)(ws + 23068672);      //  2 MB
  u16* qkvb   = (u16*)(ws + 25165824);      // 48 MB
  u16* yb     = (u16*)(ws + 75497472);      // 16 MB
  u16* vtb    = (u16*)(ws);                 // 16 MB, reuses xb (stream-ordered)

  cast3_kernel<<<12288, 256, 0, stream>>>(x, xb, 2097152,
                                          w_qkv, wqkvb, 786432,
                                          w_proj, wprojb, 262144);

  gemm_bt<1, 1><<<dim3(Mn / 128, NQKV / 128), 256, 0, stream>>>(
      xb, wqkvb, (void*)qkvb, nullptr, NQKV, Cn);

  transpose_v<<<dim3(Tn / 64, Hn, Bn), 256, 0, stream>>>(qkvb, vtb);

  attn_kernel<<<dim3(8, Hn, Bn), 256, 0, stream>>>(qkvb, vtb, yb);

  gemm_bt<0, 0><<<dim3(Mn / 128, Cn / 128), 256, 0, stream>>>(
      yb, wprojb, (void*)out, b_proj, Cn, Cn);
}

// Round 6
// 244.195 us; speedup vs baseline: 1.3887x; 1.0356x over previous
//
#include <hip/hip_runtime.h>
#include <stdint.h>

// MHA forward, B=8 T=1024 C=1024 H=16 D=64.
// fused cast fp32->bf16 -> QKV GEMM (bf16 MFMA; writes packed QK buffer
// [stride 2048, Q pre-scaled by 0.125*log2e] and V^T directly)
// -> flash attention (64-row q-tile pairs, DPP softmax, dbuf DMA)
// -> proj GEMM (+bias). 4 launches total.

#define Bn 8
#define Tn 1024
#define Cn 1024
#define Hn 16
#define Dn 64
#define Mn (Bn * Tn)      // 8192
#define NQKV (3 * Cn)     // 3072
#define QKS 2048          // packed QK row stride

typedef unsigned short u16;
typedef float f32x4 __attribute__((ext_vector_type(4)));
typedef __bf16 bf16x8 __attribute__((ext_vector_type(8)));
typedef unsigned short ushx8 __attribute__((ext_vector_type(8)));
typedef unsigned short ushx4 __attribute__((ext_vector_type(4)));

__device__ __forceinline__ u16 f2bf(float f) {
  unsigned int u = __float_as_uint(f);
  u += 0x7fffu + ((u >> 16) & 1u);   // RTN-even
  return (u16)(u >> 16);
}
__device__ __forceinline__ u16 f2bf_rna(float f) {
  return (u16)((__float_as_uint(f) + 0x8000u) >> 16);
}

__device__ __forceinline__ f32x4 mfma_bf16(ushx8 a, ushx8 b, f32x4 c) {
  return __builtin_amdgcn_mfma_f32_16x16x32_bf16(
      __builtin_bit_cast(bf16x8, a), __builtin_bit_cast(bf16x8, b), c, 0, 0, 0);
}

// async global->LDS, 16B per lane; LDS dest = wave-uniform base + lane*16 (m104)
__device__ __forceinline__ void async16(const u16* g, u16* l) {
  __builtin_amdgcn_global_load_lds(
      (__attribute__((address_space(1))) void*)(void*)g,
      (__attribute__((address_space(3))) void*)l, 16, 0, 0);
}

// ---- DPP 16-lane butterfly reductions (VALU-rate, no LDS pipe) ----
template <int CTRL>
__device__ __forceinline__ float dppmov(float v) {
  return __builtin_bit_cast(float, __builtin_amdgcn_update_dpp(
      0, __builtin_bit_cast(int, v), CTRL, 0xf, 0xf, true));
}
__device__ __forceinline__ float red16max(float v) {
  v = fmaxf(v, dppmov<0xB1>(v));
  v = fmaxf(v, dppmov<0x4E>(v));
  v = fmaxf(v, dppmov<0x141>(v));
  v = fmaxf(v, dppmov<0x140>(v));
  return v;
}
__device__ __forceinline__ float red16sum(float v) {
  v += dppmov<0xB1>(v);
  v += dppmov<0x4E>(v);
  v += dppmov<0x141>(v);
  v += dppmov<0x140>(v);
  return v;
}

// ---------------- fused cast fp32 -> bf16 (3 tensors, 1 launch) ----------------
__global__ void cast3_kernel(const float* __restrict__ a, u16* __restrict__ oa, int na4,
                             const float* __restrict__ b, u16* __restrict__ ob, int nb4,
                             const float* __restrict__ c, u16* __restrict__ oc, int nc4) {
  int i = blockIdx.x * blockDim.x + threadIdx.x;
  const float* in;
  u16* out;
  if (i < na4) { in = a; out = oa; }
  else if (i < na4 + nb4) { in = b; out = ob; i -= na4; }
  else if (i < na4 + nb4 + nc4) { in = c; out = oc; i -= na4 + nb4; }
  else return;
  float4 v = ((const float4*)in)[i];
  ushx4 o = { f2bf(v.x), f2bf(v.y), f2bf(v.z), f2bf(v.w) };
  ((ushx4*)out)[i] = o;
}

// ---------------- GEMM: C[m,n] = sum_k A[m,k]*Bw[n,k] ----------------
// QKV=1: N=3072 logical cols. Cols [0,2048) -> packed QK buffer (stride 2048),
//        Q cols scaled by 0.125*log2e. Cols [2048,3072) -> V^T (vt[b][h][d][t])
//        via packed 8B stores (lane's 4 acc regs = 4 consecutive t).
// QKV=0: fp32 out + bias, stride N.
#define SLOG2E 0.18033688011112042f
template <int QKV>
__global__ __launch_bounds__(256, 4) void gemm_bt(
    const u16* __restrict__ A, const u16* __restrict__ Bw,
    void* __restrict__ Cout, u16* __restrict__ vt,
    const float* __restrict__ bias, int N, int K) {
  __shared__ alignas(16) u16 As[128 * 32];
  __shared__ alignas(16) u16 Bs[128 * 32];

  const int tid = threadIdx.x;
  const int lane = tid & 63;
  const int wv = tid >> 6;
  const int quad = lane >> 4;
  const int l16 = lane & 15;
  const int m0 = blockIdx.x * 128;
  const int n0 = blockIdx.y * 128;
  const int wm = (wv >> 1) * 64;
  const int wn = (wv & 1) * 64;

  f32x4 acc[4][4];
#pragma unroll
  for (int i = 0; i < 4; ++i)
#pragma unroll
    for (int j = 0; j < 4; ++j) acc[i][j] = (f32x4){0.f, 0.f, 0.f, 0.f};

  const int r0 = tid >> 2;
  const int cc0 = tid & 3;
  const int gkc0 = cc0 ^ ((r0 >> 1) & 3);
  const int r1 = r0 + 64;
  const int gkc1 = cc0 ^ ((r1 >> 1) & 3);
  const u16* gA0 = A + (size_t)(m0 + r0) * K + gkc0 * 8;
  const u16* gA1 = A + (size_t)(m0 + r1) * K + gkc1 * 8;
  const u16* gB0 = Bw + (size_t)(n0 + r0) * K + gkc0 * 8;
  const u16* gB1 = Bw + (size_t)(n0 + r1) * K + gkc1 * 8;
  u16* lA0 = As + tid * 8;
  u16* lA1 = As + (256 + tid) * 8;
  u16* lB0 = Bs + tid * 8;
  u16* lB1 = Bs + (256 + tid) * 8;

  const u16* pa[4];
  const u16* pb[4];
#pragma unroll
  for (int mi = 0; mi < 4; ++mi) {
    int ra = wm + mi * 16 + l16;
    pa[mi] = As + ra * 32 + (quad ^ ((ra >> 1) & 3)) * 8;
    int rb = wn + mi * 16 + l16;
    pb[mi] = Bs + rb * 32 + (quad ^ ((rb >> 1) & 3)) * 8;
  }

  for (int k0 = 0; k0 < K; k0 += 32) {
    async16(gA0 + k0, lA0);
    async16(gA1 + k0, lA1);
    async16(gB0 + k0, lB0);
    async16(gB1 + k0, lB1);
    __syncthreads();
    ushx8 af[4], bf[4];
#pragma unroll
    for (int i = 0; i < 4; ++i) {
      af[i] = *(const ushx8*)pa[i];
      bf[i] = *(const ushx8*)pb[i];
    }
#pragma unroll
    for (int mi = 0; mi < 4; ++mi)
#pragma unroll
      for (int ni = 0; ni < 4; ++ni)
        acc[mi][ni] = mfma_bf16(af[mi], bf[ni], acc[mi][ni]);
    __syncthreads();
  }

  if constexpr (QKV) {
    if (n0 < 2 * Cn) {
      // packed QK buffer, stride 2048; scale Q cols by SLOG2E
#pragma unroll
      for (int mi = 0; mi < 4; ++mi) {
#pragma unroll
        for (int ni = 0; ni < 4; ++ni) {
          int col = n0 + wn + ni * 16 + l16;
          float sc = (col < Cn) ? SLOG2E : 1.f;
#pragma unroll
          for (int i = 0; i < 4; ++i) {
            int row = m0 + wm + mi * 16 + quad * 4 + i;
            ((u16*)Cout)[(size_t)row * QKS + col] = f2bf(acc[mi][ni][i] * sc);
          }
        }
      }
    } else {
      // V^T: lane's regs i=0..3 are consecutive t -> one 8B packed store
#pragma unroll
      for (int mi = 0; mi < 4; ++mi) {
#pragma unroll
        for (int ni = 0; ni < 4; ++ni) {
          int colV = n0 + wn + ni * 16 + l16 - 2 * Cn;  // 0..1023
          int hh = colV >> 6, dd = colV & 63;
          int row0 = m0 + wm + mi * 16 + quad * 4;
          int bb = row0 >> 10, tt = row0 & 1023;
          unsigned int lo = (unsigned int)f2bf(acc[mi][ni][0]) |
                            ((unsigned int)f2bf(acc[mi][ni][1]) << 16);
          unsigned int hi = (unsigned int)f2bf(acc[mi][ni][2]) |
                            ((unsigned int)f2bf(acc[mi][ni][3]) << 16);
          uint2 pk = {lo, hi};
          *(uint2*)&vt[((size_t)(bb * Hn + hh) * Dn + dd) * Tn + tt] = pk;
        }
      }
    }
  } else {
#pragma unroll
    for (int mi = 0; mi < 4; ++mi) {
#pragma unroll
      for (int ni = 0; ni < 4; ++ni) {
        int col = n0 + wn + ni * 16 + l16;
        float bv = bias[col];
#pragma unroll
        for (int i = 0; i < 4; ++i) {
          int row = m0 + wm + mi * 16 + quad * 4 + i;
          ((float*)Cout)[(size_t)row * N + col] = acc[mi][ni][i] + bv;
        }
      }
    }
  }
}

// ---------------- flash attention ----------------
// 1024 blocks (8,16,8); block j does 64-row q-tiles j and 15-j (17 kv-tiles —
// perfectly balanced). 3 blocks/CU. Wave wv owns q rows [wv*16, wv*16+16).
// Double-buffered async K/V^T staging; DPP reductions; raw v_exp_f32;
// Q pre-scaled in QKV GEMM (S already in log2 domain). QK stride = 2048.
__global__ __launch_bounds__(256, 3) void attn_kernel(
    const u16* __restrict__ qk, const u16* __restrict__ vt,
    u16* __restrict__ out) {
  const int j = blockIdx.x, h = blockIdx.y, b = blockIdx.z;
  const int tid = threadIdx.x;
  const int lane = tid & 63;
  const int wv = tid >> 6;
  const int quad = lane >> 4;
  const int l16 = lane & 15;

  __shared__ alignas(16) u16 Ks[2][64 * 64];   // [buf][kv][d] XOR-swizzled
  __shared__ alignas(16) u16 Vts[2][64 * 64];  // [buf][d][kv] XOR-swizzled
  __shared__ alignas(16) u16 Ps[4][16 * 72];   // per-wave P

  const u16* qb = qk + (size_t)b * Tn * QKS + h * Dn;
  const u16* kb = qk + (size_t)b * Tn * QKS + Cn + h * Dn;
  const u16* vtb = vt + (size_t)(b * Hn + h) * Dn * Tn;

  const int srow = tid >> 3;  // 0..31
  const int scc = tid & 7;
  u16* pswv = Ps[wv];

#pragma unroll 1
  for (int ph = 0; ph < 2; ++ph) {
    const int qt = ph ? (15 - j) : j;
    const int q0 = qt * 64;
    const int ntiles = qt + 1;

    // Q fragments (A-operand: m=l16, k=quad*8+jj); already scaled by SLOG2E
    ushx8 qf[2];
    {
      const u16* qp = qb + (size_t)(q0 + wv * 16 + l16) * QKS + quad * 8;
      qf[0] = *(const ushx8*)qp;
      qf[1] = *(const ushx8*)(qp + 32);
    }

    f32x4 o[4];
#pragma unroll
    for (int nt = 0; nt < 4; ++nt) o[nt] = (f32x4){0.f, 0.f, 0.f, 0.f};
    float mrow[4], lrow[4];
#pragma unroll
    for (int i = 0; i < 4; ++i) { mrow[i] = -__builtin_inff(); lrow[i] = 0.f; }

    __syncthreads();  // previous phase's compute done before overwriting buf0

    // prefetch tile 0 -> buf 0
#pragma unroll
    for (int c = 0; c < 2; ++c) {
      const int row = c * 32 + srow;
      const int gc = scc ^ (row & 7);
      async16(kb + (size_t)row * QKS + gc * 8, Ks[0] + (c * 256 + tid) * 8);
      async16(vtb + (size_t)row * Tn + gc * 8, Vts[0] + (c * 256 + tid) * 8);
    }

#pragma unroll 1
    for (int t = 0; t < ntiles; ++t) {
      const int kv0 = t * 64;
      const int bi = t & 1;
      __syncthreads();  // drains DMA for buf[bi]; all waves done with buf[bi^1]

      if (t + 1 < ntiles) {
        const int nkv0 = kv0 + 64;
        u16* kd = Ks[bi ^ 1];
        u16* vd = Vts[bi ^ 1];
#pragma unroll
        for (int c = 0; c < 2; ++c) {
          const int row = c * 32 + srow;
          const int gc = scc ^ (row & 7);
          async16(kb + (size_t)(nkv0 + row) * QKS + gc * 8, kd + (c * 256 + tid) * 8);
          async16(vtb + (size_t)row * Tn + nkv0 + gc * 8, vd + (c * 256 + tid) * 8);
        }
      }

      // S = Q K^T (already log2-scaled via Q)
      const u16* ks = Ks[bi];
      const u16* vs = Vts[bi];
      f32x4 s[4];
#pragma unroll
      for (int nt = 0; nt < 4; ++nt) s[nt] = (f32x4){0.f, 0.f, 0.f, 0.f};
#pragma unroll
      for (int nt = 0; nt < 4; ++nt) {
        const int rb = nt * 16 + l16;
        ushx8 b0 = *(const ushx8*)(ks + rb * 64 + (quad ^ (rb & 7)) * 8);
        ushx8 b1 = *(const ushx8*)(ks + rb * 64 + ((quad + 4) ^ (rb & 7)) * 8);
        s[nt] = mfma_bf16(qf[0], b0, s[nt]);
        s[nt] = mfma_bf16(qf[1], b1, s[nt]);
      }

      // online softmax (log2 domain), DPP reductions, raw v_exp_f32
      const bool dz = (kv0 + 64 > q0 + wv * 16);
#pragma unroll
      for (int i = 0; i < 4; ++i) {
        const int qr = q0 + wv * 16 + quad * 4 + i;
        float vv[4];
        float rmax = -__builtin_inff();
#pragma unroll
        for (int nt = 0; nt < 4; ++nt) {
          float v = s[nt][i];
          if (dz && (kv0 + nt * 16 + l16) > qr) v = -__builtin_inff();
          vv[nt] = v;
          rmax = fmaxf(rmax, v);
        }
        rmax = red16max(rmax);
        const float mnew = fmaxf(mrow[i], rmax);
        const float al = __builtin_amdgcn_exp2f(mrow[i] - mnew);
        mrow[i] = mnew;
        float rsum = 0.f;
#pragma unroll
        for (int nt = 0; nt < 4; ++nt) {
          float p = __builtin_amdgcn_exp2f(vv[nt] - mnew);
          rsum += p;
          pswv[(quad * 4 + i) * 72 + nt * 16 + l16] = f2bf_rna(p);
        }
        rsum = red16sum(rsum);
        lrow[i] = lrow[i] * al + rsum;
#pragma unroll
        for (int nt = 0; nt < 4; ++nt) o[nt][i] *= al;
      }

      // P A-fragments from wave-local LDS (DS in-order per wave, no barrier)
      ushx8 pf0, pf1;
      {
        const u16* pp = pswv + l16 * 72 + quad * 8;
        pf0 = *(const ushx8*)pp;
        pf1 = *(const ushx8*)(pp + 32);
      }

      // O += P V
#pragma unroll
      for (int nt = 0; nt < 4; ++nt) {
        const int rb = nt * 16 + l16;
        ushx8 v0 = *(const ushx8*)(vs + rb * 64 + (quad ^ (rb & 7)) * 8);
        ushx8 v1 = *(const ushx8*)(vs + rb * 64 + ((quad + 4) ^ (rb & 7)) * 8);
        o[nt] = mfma_bf16(pf0, v0, o[nt]);
        o[nt] = mfma_bf16(pf1, v1, o[nt]);
      }
    }

    // O/l, write y_attn as (B,T,C) bf16
#pragma unroll
    for (int i = 0; i < 4; ++i) {
      const float inv = 1.f / lrow[i];
      const int t = q0 + wv * 16 + quad * 4 + i;
      u16* op = out + ((size_t)(b * Tn + t)) * Cn + h * Dn + l16;
#pragma unroll
      for (int nt = 0; nt < 4; ++nt) op[nt * 16] = f2bf(o[nt][i] * inv);
    }
  }
}

// ---------------- launch ----------------
extern "C" void kernel_launch(void* const* d_in, const int* in_sizes, int n_in,
                              void* d_out, int out_size, void* d_ws, size_t ws_size,
                              hipStream_t stream) {
  const float* x = (const float*)d_in[0];
  const float* w_qkv = (const float*)d_in[1];
  const float* w_proj = (const float*)d_in[2];
  const float* b_proj = (const float*)d_in[3];
  float* out = (float*)d_out;
  char* ws = (char*)d_ws;

  u16* xb     = (u16*)(ws);                 // 16 MiB @ 0
  u16* wqkvb  = (u16*)(ws + 16777216);      //  6 MiB @ 16
  u16* wprojb = (u16*)(ws + 23068672);      //  2 MiB @ 22 (unused gap ok)
  u16* qkb    = (u16*)(ws + 25165824);      // 32 MiB @ 24  (packed QK, stride 2048)
  u16* vtb    = (u16*)(ws + 58720256);      // 16 MiB @ 56
  u16* yb     = (u16*)(ws + 75497472);      // 16 MiB @ 72  (ends 88 MiB, proven size)

  cast3_kernel<<<12288, 256, 0, stream>>>(x, xb, 2097152,
                                          w_qkv, wqkvb, 786432,
                                          w_proj, wprojb, 262144);

  gemm_bt<1><<<dim3(Mn / 128, NQKV / 128), 256, 0, stream>>>(
      xb, wqkvb, (void*)qkb, vtb, nullptr, NQKV, Cn);

  attn_kernel<<<dim3(8, Hn, Bn), 256, 0, stream>>>(qkb, vtb, yb);

  gemm_bt<0><<<dim3(Mn / 128, Cn / 128), 256, 0, stream>>>(
      yb, wprojb, (void*)out, nullptr, b_proj, Cn, Cn);
}